// Round 1
// baseline (1549.762 us; speedup 1.0000x reference)
//
#include <hip/hip_runtime.h>
#include <math.h>

#define BM 128
#define BN 128
#define BK 32

// ---------------------------------------------------------------------------
// zero rowsum accumulator (avoid hipMemsetAsync to be safe under graph capture)
__global__ __launch_bounds__(256) void zero_kernel(float* __restrict__ p, int n) {
    int i = blockIdx.x * 256 + threadIdx.x;
    if (i < n) p[i] = 0.f;
}

// ---------------------------------------------------------------------------
// Pass 1: adjacency[i][j] = exp(-relu(sum_d |F[i][d]-F[j][d]| * a[d]))
// plus per-row sums (atomicAdd of wave-reduced partials).
// 128x128 tile per block, 256 threads, 8x8 per thread (2x4 split per dim).
__global__ __launch_bounds__(256) void adj_kernel(
    const float* __restrict__ F, const float* __restrict__ A,
    float* __restrict__ adj, float* __restrict__ rowsum, int n, int d)
{
    __shared__ __align__(16) float As[BK][BM + 4];  // k-major, +4 pad
    __shared__ __align__(16) float Bs[BK][BN + 4];
    __shared__ float aw[256];                       // d <= 256

    const int t  = threadIdx.x;
    const int tx = t & 15;        // 0..15
    const int ty = t >> 4;        // 0..15
    const int i0 = blockIdx.y * BM;
    const int j0 = blockIdx.x * BN;

    for (int k = t; k < d; k += 256) aw[k] = A[k];

    float acc[2][2][4][4] = {};   // [rowHalf][colHalf][m][c]

    const int lr = t >> 3;        // 0..31  (row within 32-row group)
    const int lk = (t & 7) << 2;  // 0,4,...,28 (k offset)

    for (int kc = 0; kc < d; kc += BK) {
        __syncthreads();          // previous iteration's reads done
        #pragma unroll
        for (int s = 0; s < 4; ++s) {
            int r = lr + 32 * s;
            float4 v = *(const float4*)(F + (size_t)(i0 + r) * d + kc + lk);
            As[lk + 0][r] = v.x; As[lk + 1][r] = v.y;
            As[lk + 2][r] = v.z; As[lk + 3][r] = v.w;
            float4 u = *(const float4*)(F + (size_t)(j0 + r) * d + kc + lk);
            Bs[lk + 0][r] = u.x; Bs[lk + 1][r] = u.y;
            Bs[lk + 2][r] = u.z; Bs[lk + 3][r] = u.w;
        }
        __syncthreads();

        #pragma unroll
        for (int k = 0; k < BK; ++k) {
            float av[2][4], bv[2][4];
            *(float4*)&av[0][0] = *(const float4*)&As[k][4 * ty];
            *(float4*)&av[1][0] = *(const float4*)&As[k][64 + 4 * ty];
            *(float4*)&bv[0][0] = *(const float4*)&Bs[k][4 * tx];
            *(float4*)&bv[1][0] = *(const float4*)&Bs[k][64 + 4 * tx];
            const float w = aw[kc + k];
            #pragma unroll
            for (int p = 0; p < 2; ++p)
                #pragma unroll
                for (int m = 0; m < 4; ++m)
                    #pragma unroll
                    for (int q = 0; q < 2; ++q)
                        #pragma unroll
                        for (int c = 0; c < 4; ++c)
                            acc[p][q][m][c] += fabsf(av[p][m] - bv[q][c]) * w;
        }
    }

    // Epilogue: exp(-relu(score)), store adjacency, accumulate row sums.
    #pragma unroll
    for (int p = 0; p < 2; ++p) {
        #pragma unroll
        for (int m = 0; m < 4; ++m) {
            const int row = i0 + p * 64 + ty * 4 + m;
            float rs = 0.f;
            #pragma unroll
            for (int q = 0; q < 2; ++q) {
                float4 v;
                v.x = __expf(-fmaxf(acc[p][q][m][0], 0.f));
                v.y = __expf(-fmaxf(acc[p][q][m][1], 0.f));
                v.z = __expf(-fmaxf(acc[p][q][m][2], 0.f));
                v.w = __expf(-fmaxf(acc[p][q][m][3], 0.f));
                rs += (v.x + v.y) + (v.z + v.w);
                *(float4*)(adj + (size_t)row * n + j0 + q * 64 + tx * 4) = v;
            }
            // reduce over the 16 tx lanes (wave64: masks 1,2,4,8 stay in 16-group)
            rs += __shfl_xor(rs, 1);
            rs += __shfl_xor(rs, 2);
            rs += __shfl_xor(rs, 4);
            rs += __shfl_xor(rs, 8);
            if (tx == 0) atomicAdd(rowsum + row, rs);
        }
    }
}

// ---------------------------------------------------------------------------
__global__ __launch_bounds__(256) void dsq_kernel(
    const float* __restrict__ rowsum, float* __restrict__ dsq, int n)
{
    int i = blockIdx.x * 256 + threadIdx.x;
    if (i < n) dsq[i] = 1.f / sqrtf(rowsum[i]);
}

// ---------------------------------------------------------------------------
// Pass 2: normalized[i][j] = dsq[i] * adj[i][j] * dsq[j]  (pure streaming)
__global__ __launch_bounds__(256) void norm_kernel(
    const float* __restrict__ adj, const float* __restrict__ dsq,
    float* __restrict__ out, int n)
{
    const int i = blockIdx.y;
    const int j = (blockIdx.x * 256 + threadIdx.x) * 4;
    if (j >= n) return;
    const float di = dsq[i];
    float4 a = *(const float4*)(adj + (size_t)i * n + j);
    float4 dj = *(const float4*)(dsq + j);
    float4 o;
    o.x = di * a.x * dj.x;
    o.y = di * a.y * dj.y;
    o.z = di * a.z * dj.z;
    o.w = di * a.w * dj.w;
    *(float4*)(out + (size_t)i * n + j) = o;
}

// ---------------------------------------------------------------------------
extern "C" void kernel_launch(void* const* d_in, const int* in_sizes, int n_in,
                              void* d_out, int out_size, void* d_ws, size_t ws_size,
                              hipStream_t stream)
{
    const float* F = (const float*)d_in[0];   // (n, d) fp32
    const float* A = (const float*)d_in[1];   // (d, 1) fp32
    const int d = in_sizes[1];                // 256
    const int n = in_sizes[0] / d;            // 8192

    float* out    = (float*)d_out;            // normalized, n*n
    float* adj    = out + (size_t)n * n;      // adjacency, n*n
    float* rowsum = (float*)d_ws;             // n floats
    float* dsq    = rowsum + n;               // n floats

    zero_kernel<<<dim3((n + 255) / 256), dim3(256), 0, stream>>>(rowsum, n);

    dim3 gridA(n / BN, n / BM);
    adj_kernel<<<gridA, dim3(256), 0, stream>>>(F, A, adj, rowsum, n, d);

    dsq_kernel<<<dim3((n + 255) / 256), dim3(256), 0, stream>>>(rowsum, dsq, n);

    dim3 gridN(n / 1024, n);  // 256 threads * 4 floats = 1024 cols per block
    norm_kernel<<<gridN, dim3(256), 0, stream>>>(adj, dsq, out, n);
}

// Round 2
// 325.700 us; speedup vs baseline: 4.7583x; 4.7583x over previous
//
#include <hip/hip_runtime.h>
#include <math.h>

#define BM 128
#define BN 128
#define BK 32

typedef unsigned int uint;

// monotonic float<->uint encoding for atomic min/max
__device__ __forceinline__ uint fenc(float f) {
    uint u = __float_as_uint(f);
    return (u & 0x80000000u) ? ~u : (u | 0x80000000u);
}
__device__ __forceinline__ float fdec(uint u) {
    uint v = (u & 0x80000000u) ? (u & 0x7FFFFFFFu) : ~u;
    return __uint_as_float(v);
}

// ---------------------------------------------------------------------------
// init: zero rowsum; init minmax/negflag scalars; scan a for negative entries
// ws layout (u32): [0]=negflag [1]=min_enc [2]=max_enc ; rowsum at +8, dsq at +8+n
__global__ __launch_bounds__(256) void init_kernel(uint* __restrict__ flags,
                                                   float* __restrict__ rowsum,
                                                   const float* __restrict__ A,
                                                   int n, int d, int zb)
{
    const int b = blockIdx.x, t = threadIdx.x;
    if (b < zb) { int i = b * 256 + t; if (i < n) rowsum[i] = 0.f; return; }
    if (t == 0) { flags[0] = 0u; flags[1] = 0xFFFFFFFFu; flags[2] = 0u; }
    __syncthreads();
    for (int k = t; k < d; k += 256)
        if (A[k] < 0.f) atomicOr(&flags[0], 1u);
}

// ---------------------------------------------------------------------------
// global min/max of G = |a_d| * F[i][d]
__global__ __launch_bounds__(256) void minmax_kernel(const float* __restrict__ F,
                                                     const float* __restrict__ A,
                                                     uint* __restrict__ flags,
                                                     int n, int d)
{
    const int total4 = n * d / 4;
    float lmin = 3.4e38f, lmax = -3.4e38f;
    for (int e4 = blockIdx.x * 256 + threadIdx.x; e4 < total4; e4 += gridDim.x * 256) {
        int e = e4 * 4;
        int dk = e % d;
        float4 f = *(const float4*)(F + e);
        float4 a = *(const float4*)(A + dk);
        float g0 = fabsf(a.x) * f.x, g1 = fabsf(a.y) * f.y;
        float g2 = fabsf(a.z) * f.z, g3 = fabsf(a.w) * f.w;
        lmin = fminf(lmin, fminf(fminf(g0, g1), fminf(g2, g3)));
        lmax = fmaxf(lmax, fmaxf(fmaxf(g0, g1), fmaxf(g2, g3)));
    }
    #pragma unroll
    for (int m = 1; m < 64; m <<= 1) {
        lmin = fminf(lmin, __shfl_xor(lmin, m));
        lmax = fmaxf(lmax, __shfl_xor(lmax, m));
    }
    if ((threadIdx.x & 63) == 0) {
        atomicMin(&flags[1], fenc(lmin));
        atomicMax(&flags[2], fenc(lmax));
    }
}

// ---------------------------------------------------------------------------
// quantize G = a_d*F (a_d>0 dims; others -> constant 0) to u8, store k-major:
// Q[u32 kq][row], kq = d/4 packed columns. Only used when negflag==0.
__global__ __launch_bounds__(256) void quant_kernel(const float* __restrict__ F,
                                                    const float* __restrict__ A,
                                                    const uint* __restrict__ flags,
                                                    uint* __restrict__ Q,
                                                    int n, int d)
{
    const int t = threadIdx.x;
    const int r = blockIdx.x * 32 + (t & 31);
    const int kqb = t >> 5;
    const int d4 = d >> 2;
    const float gmin = fdec(flags[1]), gmax = fdec(flags[2]);
    const float span = gmax - gmin;
    const float inv = span > 0.f ? 255.f / span : 0.f;
    for (int kq = kqb; kq < d4; kq += 8) {
        float4 f = *(const float4*)(F + (size_t)r * d + kq * 4);
        float4 a = *(const float4*)(A + kq * 4);
        uint q0 = 0, q1 = 0, q2 = 0, q3 = 0;
        if (a.x > 0.f) q0 = (uint)fminf(fmaxf((a.x * f.x - gmin) * inv + 0.5f, 0.f), 255.f);
        if (a.y > 0.f) q1 = (uint)fminf(fmaxf((a.y * f.y - gmin) * inv + 0.5f, 0.f), 255.f);
        if (a.z > 0.f) q2 = (uint)fminf(fmaxf((a.z * f.z - gmin) * inv + 0.5f, 0.f), 255.f);
        if (a.w > 0.f) q3 = (uint)fminf(fmaxf((a.w * f.w - gmin) * inv + 0.5f, 0.f), 255.f);
        Q[(size_t)kq * n + r] = q0 | (q1 << 8) | (q2 << 16) | (q3 << 24);
    }
}

// ---------------------------------------------------------------------------
// Fast path (negflag==0): adjacency via v_sad_u8. 128x128 tile, 8x8/thread.
__global__ __launch_bounds__(256) void adj_sad_kernel(const uint* __restrict__ Q,
                                                      const uint* __restrict__ flags,
                                                      float* __restrict__ adj,
                                                      float* __restrict__ rowsum,
                                                      int n, int d)
{
    if (flags[0] != 0u) return;   // negative weights -> fp32 fallback handles it

    __shared__ uint As[16][128];
    __shared__ uint Bs[16][128];

    const int t = threadIdx.x, tx = t & 15, ty = t >> 4;
    const int i0 = blockIdx.y * 128, j0 = blockIdx.x * 128;
    const int d4 = d >> 2, chunks = d4 >> 4;

    const float gmin = fdec(flags[1]), gmax = fdec(flags[2]);
    const float step = (gmax - gmin) * (1.f / 255.f);

    uint acc[8][8] = {};

    const int kk0 = t >> 5;          // 0..7
    const int col = 4 * (t & 31);    // 0,4,...,124

    uint4 sa[2], sb[2];
    #pragma unroll
    for (int j = 0; j < 2; ++j) {
        size_t g = ((size_t)(kk0 + 8 * j)) * n;
        sa[j] = *(const uint4*)(Q + g + i0 + col);
        sb[j] = *(const uint4*)(Q + g + j0 + col);
    }

    for (int c = 0; c < chunks; ++c) {
        ((uint4*)&As[0][0])[t]       = sa[0];
        ((uint4*)&As[0][0])[256 + t] = sa[1];
        ((uint4*)&Bs[0][0])[t]       = sb[0];
        ((uint4*)&Bs[0][0])[256 + t] = sb[1];
        __syncthreads();

        if (c + 1 < chunks) {
            #pragma unroll
            for (int j = 0; j < 2; ++j) {
                size_t g = ((size_t)((c + 1) * 16 + kk0 + 8 * j)) * n;
                sa[j] = *(const uint4*)(Q + g + i0 + col);
                sb[j] = *(const uint4*)(Q + g + j0 + col);
            }
        }

        #pragma unroll
        for (int kk = 0; kk < 16; ++kk) {
            uint ar[8], br[8];
            *(uint4*)&ar[0] = *(const uint4*)&As[kk][4 * ty];
            *(uint4*)&ar[4] = *(const uint4*)&As[kk][64 + 4 * ty];
            *(uint4*)&br[0] = *(const uint4*)&Bs[kk][4 * tx];
            *(uint4*)&br[4] = *(const uint4*)&Bs[kk][64 + 4 * tx];
            #pragma unroll
            for (int m = 0; m < 8; ++m)
                #pragma unroll
                for (int cc = 0; cc < 8; ++cc)
                    acc[m][cc] = __builtin_amdgcn_sad_u8(ar[m], br[cc], acc[m][cc]);
        }
        __syncthreads();
    }

    // epilogue: score = step*acc ; adj = exp(-relu(score)) ; rowsum atomics
    #pragma unroll
    for (int m = 0; m < 8; ++m) {
        const int row = i0 + (m >> 2) * 64 + 4 * ty + (m & 3);
        float rs = 0.f;
        #pragma unroll
        for (int qh = 0; qh < 2; ++qh) {
            float4 v;
            v.x = __expf(-fmaxf(step * (float)acc[m][qh * 4 + 0], 0.f));
            v.y = __expf(-fmaxf(step * (float)acc[m][qh * 4 + 1], 0.f));
            v.z = __expf(-fmaxf(step * (float)acc[m][qh * 4 + 2], 0.f));
            v.w = __expf(-fmaxf(step * (float)acc[m][qh * 4 + 3], 0.f));
            rs += (v.x + v.y) + (v.z + v.w);
            *(float4*)(adj + (size_t)row * n + j0 + qh * 64 + 4 * tx) = v;
        }
        rs += __shfl_xor(rs, 1);
        rs += __shfl_xor(rs, 2);
        rs += __shfl_xor(rs, 4);
        rs += __shfl_xor(rs, 8);
        if (tx == 0) atomicAdd(rowsum + row, rs);
    }
}

// ---------------------------------------------------------------------------
// Slow fp32 fallback (negflag!=0): round-1 kernel, known correct.
__global__ __launch_bounds__(256) void adj_kernel(
    const float* __restrict__ F, const float* __restrict__ A,
    const uint* __restrict__ flags,
    float* __restrict__ adj, float* __restrict__ rowsum, int n, int d)
{
    if (flags[0] == 0u) return;   // fast path handled it

    __shared__ __align__(16) float As[BK][BM + 4];
    __shared__ __align__(16) float Bs[BK][BN + 4];
    __shared__ float aw[256];

    const int t  = threadIdx.x;
    const int tx = t & 15;
    const int ty = t >> 4;
    const int i0 = blockIdx.y * BM;
    const int j0 = blockIdx.x * BN;

    for (int k = t; k < d; k += 256) aw[k] = A[k];

    float acc[2][2][4][4] = {};

    const int lr = t >> 3;
    const int lk = (t & 7) << 2;

    for (int kc = 0; kc < d; kc += BK) {
        __syncthreads();
        #pragma unroll
        for (int s = 0; s < 4; ++s) {
            int r = lr + 32 * s;
            float4 v = *(const float4*)(F + (size_t)(i0 + r) * d + kc + lk);
            As[lk + 0][r] = v.x; As[lk + 1][r] = v.y;
            As[lk + 2][r] = v.z; As[lk + 3][r] = v.w;
            float4 u = *(const float4*)(F + (size_t)(j0 + r) * d + kc + lk);
            Bs[lk + 0][r] = u.x; Bs[lk + 1][r] = u.y;
            Bs[lk + 2][r] = u.z; Bs[lk + 3][r] = u.w;
        }
        __syncthreads();

        #pragma unroll
        for (int k = 0; k < BK; ++k) {
            float av[2][4], bv[2][4];
            *(float4*)&av[0][0] = *(const float4*)&As[k][4 * ty];
            *(float4*)&av[1][0] = *(const float4*)&As[k][64 + 4 * ty];
            *(float4*)&bv[0][0] = *(const float4*)&Bs[k][4 * tx];
            *(float4*)&bv[1][0] = *(const float4*)&Bs[k][64 + 4 * tx];
            const float w = aw[kc + k];
            #pragma unroll
            for (int p = 0; p < 2; ++p)
                #pragma unroll
                for (int m = 0; m < 4; ++m)
                    #pragma unroll
                    for (int q = 0; q < 2; ++q)
                        #pragma unroll
                        for (int c = 0; c < 4; ++c)
                            acc[p][q][m][c] += fabsf(av[p][m] - bv[q][c]) * w;
        }
    }

    #pragma unroll
    for (int p = 0; p < 2; ++p) {
        #pragma unroll
        for (int m = 0; m < 4; ++m) {
            const int row = i0 + p * 64 + ty * 4 + m;
            float rs = 0.f;
            #pragma unroll
            for (int q = 0; q < 2; ++q) {
                float4 v;
                v.x = __expf(-fmaxf(acc[p][q][m][0], 0.f));
                v.y = __expf(-fmaxf(acc[p][q][m][1], 0.f));
                v.z = __expf(-fmaxf(acc[p][q][m][2], 0.f));
                v.w = __expf(-fmaxf(acc[p][q][m][3], 0.f));
                rs += (v.x + v.y) + (v.z + v.w);
                *(float4*)(adj + (size_t)row * n + j0 + q * 64 + tx * 4) = v;
            }
            rs += __shfl_xor(rs, 1);
            rs += __shfl_xor(rs, 2);
            rs += __shfl_xor(rs, 4);
            rs += __shfl_xor(rs, 8);
            if (tx == 0) atomicAdd(rowsum + row, rs);
        }
    }
}

// ---------------------------------------------------------------------------
__global__ __launch_bounds__(256) void dsq_kernel(
    const float* __restrict__ rowsum, float* __restrict__ dsq, int n)
{
    int i = blockIdx.x * 256 + threadIdx.x;
    if (i < n) dsq[i] = 1.f / sqrtf(rowsum[i]);
}

// ---------------------------------------------------------------------------
__global__ __launch_bounds__(256) void norm_kernel(
    const float* __restrict__ adj, const float* __restrict__ dsq,
    float* __restrict__ out, int n)
{
    const int i = blockIdx.y;
    const int j = (blockIdx.x * 256 + threadIdx.x) * 4;
    if (j >= n) return;
    const float di = dsq[i];
    float4 a = *(const float4*)(adj + (size_t)i * n + j);
    float4 dj = *(const float4*)(dsq + j);
    float4 o;
    o.x = di * a.x * dj.x;
    o.y = di * a.y * dj.y;
    o.z = di * a.z * dj.z;
    o.w = di * a.w * dj.w;
    *(float4*)(out + (size_t)i * n + j) = o;
}

// ---------------------------------------------------------------------------
extern "C" void kernel_launch(void* const* d_in, const int* in_sizes, int n_in,
                              void* d_out, int out_size, void* d_ws, size_t ws_size,
                              hipStream_t stream)
{
    const float* F = (const float*)d_in[0];   // (n, d) fp32
    const float* A = (const float*)d_in[1];   // (d, 1) fp32
    const int d = in_sizes[1];                // 256
    const int n = in_sizes[0] / d;            // 8192

    float* out    = (float*)d_out;            // normalized, n*n
    float* adj    = out + (size_t)n * n;      // adjacency, n*n
    uint*  flags  = (uint*)d_ws;              // [0]=negflag [1]=min [2]=max
    float* rowsum = (float*)d_ws + 8;
    float* dsq    = rowsum + n;
    // quantized features (k-major u32 [d/4][n]) live in the normalized output
    // region (2 MB << 256 MB); overwritten by norm_kernel afterwards.
    uint* Q = (uint*)d_out;

    const int zb = (n + 255) / 256;
    init_kernel<<<dim3(zb + 1), dim3(256), 0, stream>>>(flags, rowsum, A, n, d, zb);
    minmax_kernel<<<dim3(256), dim3(256), 0, stream>>>(F, A, flags, n, d);
    quant_kernel<<<dim3(n / 32), dim3(256), 0, stream>>>(F, A, flags, Q, n, d);

    dim3 gridA(n / 128, n / 128);
    adj_sad_kernel<<<gridA, dim3(256), 0, stream>>>(Q, flags, adj, rowsum, n, d);
    adj_kernel<<<gridA, dim3(256), 0, stream>>>(F, A, flags, adj, rowsum, n, d);

    dsq_kernel<<<dim3((n + 255) / 256), dim3(256), 0, stream>>>(rowsum, dsq, n);

    dim3 gridN(n / 1024, n);
    norm_kernel<<<gridN, dim3(256), 0, stream>>>(adj, dsq, out, n);
}

// Round 3
// 323.581 us; speedup vs baseline: 4.7894x; 1.0065x over previous
//
#include <hip/hip_runtime.h>
#include <math.h>

#define BM 128
#define BN 128
#define BK 32

typedef unsigned int uint;

// monotonic float<->uint encoding for atomic min/max
__device__ __forceinline__ uint fenc(float f) {
    uint u = __float_as_uint(f);
    return (u & 0x80000000u) ? ~u : (u | 0x80000000u);
}
__device__ __forceinline__ float fdec(uint u) {
    uint v = (u & 0x80000000u) ? (u & 0x7FFFFFFFu) : ~u;
    return __uint_as_float(v);
}

// ---------------------------------------------------------------------------
// init: zero rowsum; init minmax/negflag scalars; scan a for negative entries
__global__ __launch_bounds__(256) void init_kernel(uint* __restrict__ flags,
                                                   float* __restrict__ rowsum,
                                                   const float* __restrict__ A,
                                                   int n, int d, int zb)
{
    const int b = blockIdx.x, t = threadIdx.x;
    if (b < zb) { int i = b * 256 + t; if (i < n) rowsum[i] = 0.f; return; }
    if (t == 0) { flags[0] = 0u; flags[1] = 0xFFFFFFFFu; flags[2] = 0u; }
    __syncthreads();
    for (int k = t; k < d; k += 256)
        if (A[k] < 0.f) atomicOr(&flags[0], 1u);
}

// ---------------------------------------------------------------------------
// global min/max of G = |a_d| * F[i][d]
__global__ __launch_bounds__(256) void minmax_kernel(const float* __restrict__ F,
                                                     const float* __restrict__ A,
                                                     uint* __restrict__ flags,
                                                     int n, int d)
{
    const int total4 = n * d / 4;
    float lmin = 3.4e38f, lmax = -3.4e38f;
    for (int e4 = blockIdx.x * 256 + threadIdx.x; e4 < total4; e4 += gridDim.x * 256) {
        int e = e4 * 4;
        int dk = e % d;
        float4 f = *(const float4*)(F + e);
        float4 a = *(const float4*)(A + dk);
        float g0 = fabsf(a.x) * f.x, g1 = fabsf(a.y) * f.y;
        float g2 = fabsf(a.z) * f.z, g3 = fabsf(a.w) * f.w;
        lmin = fminf(lmin, fminf(fminf(g0, g1), fminf(g2, g3)));
        lmax = fmaxf(lmax, fmaxf(fmaxf(g0, g1), fmaxf(g2, g3)));
    }
    #pragma unroll
    for (int m = 1; m < 64; m <<= 1) {
        lmin = fminf(lmin, __shfl_xor(lmin, m));
        lmax = fmaxf(lmax, __shfl_xor(lmax, m));
    }
    if ((threadIdx.x & 63) == 0) {
        atomicMin(&flags[1], fenc(lmin));
        atomicMax(&flags[2], fenc(lmax));
    }
}

// ---------------------------------------------------------------------------
// quantize G = a_d*F (a_d>0 dims; others -> 0) to u8, k-major u32 [d/4][n]
__global__ __launch_bounds__(256) void quant_kernel(const float* __restrict__ F,
                                                    const float* __restrict__ A,
                                                    const uint* __restrict__ flags,
                                                    uint* __restrict__ Q,
                                                    int n, int d)
{
    const int t = threadIdx.x;
    const int r = blockIdx.x * 32 + (t & 31);
    const int kqb = t >> 5;
    const int d4 = d >> 2;
    const float gmin = fdec(flags[1]), gmax = fdec(flags[2]);
    const float span = gmax - gmin;
    const float inv = span > 0.f ? 255.f / span : 0.f;
    for (int kq = kqb; kq < d4; kq += 8) {
        float4 f = *(const float4*)(F + (size_t)r * d + kq * 4);
        float4 a = *(const float4*)(A + kq * 4);
        uint q0 = 0, q1 = 0, q2 = 0, q3 = 0;
        if (a.x > 0.f) q0 = (uint)fminf(fmaxf((a.x * f.x - gmin) * inv + 0.5f, 0.f), 255.f);
        if (a.y > 0.f) q1 = (uint)fminf(fmaxf((a.y * f.y - gmin) * inv + 0.5f, 0.f), 255.f);
        if (a.z > 0.f) q2 = (uint)fminf(fmaxf((a.z * f.z - gmin) * inv + 0.5f, 0.f), 255.f);
        if (a.w > 0.f) q3 = (uint)fminf(fmaxf((a.w * f.w - gmin) * inv + 0.5f, 0.f), 255.f);
        Q[(size_t)kq * n + r] = q0 | (q1 << 8) | (q2 << 16) | (q3 << 24);
    }
}

// ---------------------------------------------------------------------------
// Fast path (negflag==0): symmetric — only lower-tri block pairs (bx >= by),
// each off-diag tile written direct + transposed; col sums folded into rowsum.
__global__ __launch_bounds__(256, 3) void adj_sad_kernel(const uint* __restrict__ Q,
                                                         const uint* __restrict__ flags,
                                                         float* __restrict__ adj,
                                                         float* __restrict__ rowsum,
                                                         int n, int d)
{
    if (flags[0] != 0u) return;   // negative weights -> fp32 fallback handles it

    __shared__ uint As[16][128];
    __shared__ uint Bs[16][128];

    // triangular block decode: b -> (bx >= by)
    int b = blockIdx.x;
    int bx = (int)((sqrtf(8.f * (float)b + 1.f) - 1.f) * 0.5f);
    while ((bx + 1) * (bx + 2) / 2 <= b) ++bx;
    while (bx * (bx + 1) / 2 > b) --bx;
    const int by = b - bx * (bx + 1) / 2;

    const int t = threadIdx.x, tx = t & 15, ty = t >> 4;
    const int i0 = by * 128;          // row block
    const int j0 = bx * 128;          // col block (>= i0)
    const bool diag = (bx == by);
    const int d4 = d >> 2, chunks = d4 >> 4;

    const float gmin = fdec(flags[1]), gmax = fdec(flags[2]);
    const float step = (gmax - gmin) * (1.f / 255.f);

    uint acc[8][8] = {};

    const int kk0 = t >> 5;          // 0..7
    const int col = 4 * (t & 31);    // 0,4,...,124

    uint4 sa[2], sb[2];
    #pragma unroll
    for (int j = 0; j < 2; ++j) {
        size_t g = ((size_t)(kk0 + 8 * j)) * n;
        sa[j] = *(const uint4*)(Q + g + i0 + col);
        sb[j] = *(const uint4*)(Q + g + j0 + col);
    }

    for (int c = 0; c < chunks; ++c) {
        ((uint4*)&As[0][0])[t]       = sa[0];
        ((uint4*)&As[0][0])[256 + t] = sa[1];
        ((uint4*)&Bs[0][0])[t]       = sb[0];
        ((uint4*)&Bs[0][0])[256 + t] = sb[1];
        __syncthreads();

        if (c + 1 < chunks) {
            #pragma unroll
            for (int j = 0; j < 2; ++j) {
                size_t g = ((size_t)((c + 1) * 16 + kk0 + 8 * j)) * n;
                sa[j] = *(const uint4*)(Q + g + i0 + col);
                sb[j] = *(const uint4*)(Q + g + j0 + col);
            }
        }

        #pragma unroll
        for (int kk = 0; kk < 16; ++kk) {
            uint ar[8], br[8];
            *(uint4*)&ar[0] = *(const uint4*)&As[kk][4 * ty];
            *(uint4*)&ar[4] = *(const uint4*)&As[kk][64 + 4 * ty];
            *(uint4*)&br[0] = *(const uint4*)&Bs[kk][4 * tx];
            *(uint4*)&br[4] = *(const uint4*)&Bs[kk][64 + 4 * tx];
            #pragma unroll
            for (int m = 0; m < 8; ++m)
                #pragma unroll
                for (int cc = 0; cc < 8; ++cc)
                    acc[m][cc] = __builtin_amdgcn_sad_u8(ar[m], br[cc], acc[m][cc]);
        }
        __syncthreads();
    }

    // epilogue: e = exp(-step*acc)  (score >= 0, relu is a no-op on fast path)
    float e[8][8];
    #pragma unroll
    for (int m = 0; m < 8; ++m)
        #pragma unroll
        for (int cc = 0; cc < 8; ++cc)
            e[m][cc] = __expf(-step * (float)acc[m][cc]);

    // direct tile: rows i0+..., cols j0+...; row sums
    #pragma unroll
    for (int m = 0; m < 8; ++m) {
        const int row = i0 + (m >> 2) * 64 + 4 * ty + (m & 3);
        float rs = 0.f;
        #pragma unroll
        for (int qh = 0; qh < 2; ++qh) {
            float4 v = make_float4(e[m][qh * 4 + 0], e[m][qh * 4 + 1],
                                   e[m][qh * 4 + 2], e[m][qh * 4 + 3]);
            rs += (v.x + v.y) + (v.z + v.w);
            *(float4*)(adj + (size_t)row * n + j0 + qh * 64 + 4 * tx) = v;
        }
        rs += __shfl_xor(rs, 1);
        rs += __shfl_xor(rs, 2);
        rs += __shfl_xor(rs, 4);
        rs += __shfl_xor(rs, 8);
        if (tx == 0) atomicAdd(rowsum + row, rs);
    }

    if (!diag) {
        // transposed tile: rows j0+..., cols i0+...
        #pragma unroll
        for (int h = 0; h < 2; ++h)
            #pragma unroll
            for (int qh = 0; qh < 2; ++qh)
                #pragma unroll
                for (int cc = 0; cc < 4; ++cc) {
                    float4 v = make_float4(e[4 * h + 0][qh * 4 + cc],
                                           e[4 * h + 1][qh * 4 + cc],
                                           e[4 * h + 2][qh * 4 + cc],
                                           e[4 * h + 3][qh * 4 + cc]);
                    const int r = j0 + qh * 64 + 4 * tx + cc;
                    *(float4*)(adj + (size_t)r * n + i0 + 64 * h + 4 * ty) = v;
                }

        // column sums -> rowsum[j0 + col] (col sums == row sums by symmetry)
        float cs[8];
        #pragma unroll
        for (int cc = 0; cc < 8; ++cc) {
            float s = 0.f;
            #pragma unroll
            for (int m = 0; m < 8; ++m) s += e[m][cc];
            s += __shfl_xor(s, 16);
            s += __shfl_xor(s, 32);
            cs[cc] = s;
        }
        if ((t & 48) == 0) {
            #pragma unroll
            for (int qh = 0; qh < 2; ++qh)
                #pragma unroll
                for (int cc = 0; cc < 4; ++cc)
                    atomicAdd(rowsum + j0 + qh * 64 + 4 * tx + cc, cs[qh * 4 + cc]);
        }
    }
}

// ---------------------------------------------------------------------------
// Slow fp32 fallback (negflag!=0): full grid, known correct.
__global__ __launch_bounds__(256) void adj_kernel(
    const float* __restrict__ F, const float* __restrict__ A,
    const uint* __restrict__ flags,
    float* __restrict__ adj, float* __restrict__ rowsum, int n, int d)
{
    if (flags[0] == 0u) return;   // fast path handled it

    __shared__ __align__(16) float As[BK][BM + 4];
    __shared__ __align__(16) float Bs[BK][BN + 4];
    __shared__ float aw[256];

    const int t  = threadIdx.x;
    const int tx = t & 15;
    const int ty = t >> 4;
    const int i0 = blockIdx.y * BM;
    const int j0 = blockIdx.x * BN;

    for (int k = t; k < d; k += 256) aw[k] = A[k];

    float acc[2][2][4][4] = {};

    const int lr = t >> 3;
    const int lk = (t & 7) << 2;

    for (int kc = 0; kc < d; kc += BK) {
        __syncthreads();
        #pragma unroll
        for (int s = 0; s < 4; ++s) {
            int r = lr + 32 * s;
            float4 v = *(const float4*)(F + (size_t)(i0 + r) * d + kc + lk);
            As[lk + 0][r] = v.x; As[lk + 1][r] = v.y;
            As[lk + 2][r] = v.z; As[lk + 3][r] = v.w;
            float4 u = *(const float4*)(F + (size_t)(j0 + r) * d + kc + lk);
            Bs[lk + 0][r] = u.x; Bs[lk + 1][r] = u.y;
            Bs[lk + 2][r] = u.z; Bs[lk + 3][r] = u.w;
        }
        __syncthreads();

        #pragma unroll
        for (int k = 0; k < BK; ++k) {
            float av[2][4], bv[2][4];
            *(float4*)&av[0][0] = *(const float4*)&As[k][4 * ty];
            *(float4*)&av[1][0] = *(const float4*)&As[k][64 + 4 * ty];
            *(float4*)&bv[0][0] = *(const float4*)&Bs[k][4 * tx];
            *(float4*)&bv[1][0] = *(const float4*)&Bs[k][64 + 4 * tx];
            const float w = aw[kc + k];
            #pragma unroll
            for (int p = 0; p < 2; ++p)
                #pragma unroll
                for (int m = 0; m < 4; ++m)
                    #pragma unroll
                    for (int q = 0; q < 2; ++q)
                        #pragma unroll
                        for (int c = 0; c < 4; ++c)
                            acc[p][q][m][c] += fabsf(av[p][m] - bv[q][c]) * w;
        }
    }

    #pragma unroll
    for (int p = 0; p < 2; ++p) {
        #pragma unroll
        for (int m = 0; m < 4; ++m) {
            const int row = i0 + p * 64 + ty * 4 + m;
            float rs = 0.f;
            #pragma unroll
            for (int q = 0; q < 2; ++q) {
                float4 v;
                v.x = __expf(-fmaxf(acc[p][q][m][0], 0.f));
                v.y = __expf(-fmaxf(acc[p][q][m][1], 0.f));
                v.z = __expf(-fmaxf(acc[p][q][m][2], 0.f));
                v.w = __expf(-fmaxf(acc[p][q][m][3], 0.f));
                rs += (v.x + v.y) + (v.z + v.w);
                *(float4*)(adj + (size_t)row * n + j0 + q * 64 + tx * 4) = v;
            }
            rs += __shfl_xor(rs, 1);
            rs += __shfl_xor(rs, 2);
            rs += __shfl_xor(rs, 4);
            rs += __shfl_xor(rs, 8);
            if (tx == 0) atomicAdd(rowsum + row, rs);
        }
    }
}

// ---------------------------------------------------------------------------
__global__ __launch_bounds__(256) void dsq_kernel(
    const float* __restrict__ rowsum, float* __restrict__ dsq, int n)
{
    int i = blockIdx.x * 256 + threadIdx.x;
    if (i < n) dsq[i] = 1.f / sqrtf(rowsum[i]);
}

// ---------------------------------------------------------------------------
// normalized[i][j] = dsq[i]*adj[i][j]*dsq[j]; 16 KB per block (4x float4/thread)
__global__ __launch_bounds__(256) void norm_kernel(
    const float* __restrict__ adj, const float* __restrict__ dsq,
    float* __restrict__ out, int n)
{
    const int i = blockIdx.y;
    const float di = dsq[i];
    const int base = blockIdx.x * 4096;
    #pragma unroll
    for (int k = 0; k < 4; ++k) {
        const int j = base + k * 1024 + threadIdx.x * 4;
        if (j >= n) return;
        float4 a = *(const float4*)(adj + (size_t)i * n + j);
        float4 dj = *(const float4*)(dsq + j);
        float4 o;
        o.x = di * a.x * dj.x;
        o.y = di * a.y * dj.y;
        o.z = di * a.z * dj.z;
        o.w = di * a.w * dj.w;
        *(float4*)(out + (size_t)i * n + j) = o;
    }
}

// ---------------------------------------------------------------------------
extern "C" void kernel_launch(void* const* d_in, const int* in_sizes, int n_in,
                              void* d_out, int out_size, void* d_ws, size_t ws_size,
                              hipStream_t stream)
{
    const float* F = (const float*)d_in[0];   // (n, d) fp32
    const float* A = (const float*)d_in[1];   // (d, 1) fp32
    const int d = in_sizes[1];                // 256
    const int n = in_sizes[0] / d;            // 8192

    float* out    = (float*)d_out;            // normalized, n*n
    float* adj    = out + (size_t)n * n;      // adjacency, n*n
    uint*  flags  = (uint*)d_ws;              // [0]=negflag [1]=min [2]=max
    float* rowsum = (float*)d_ws + 8;
    float* dsq    = rowsum + n;
    uint* Q = (uint*)d_out;                   // k-major u8x4, 2 MB, in out region

    const int zb = (n + 255) / 256;
    init_kernel<<<dim3(zb + 1), dim3(256), 0, stream>>>(flags, rowsum, A, n, d, zb);
    minmax_kernel<<<dim3(256), dim3(256), 0, stream>>>(F, A, flags, n, d);
    quant_kernel<<<dim3(n / 32), dim3(256), 0, stream>>>(F, A, flags, Q, n, d);

    const int nb = n / 128;
    const int tri = nb * (nb + 1) / 2;
    adj_sad_kernel<<<dim3(tri), dim3(256), 0, stream>>>(Q, flags, adj, rowsum, n, d);
    adj_kernel<<<dim3(nb, nb), dim3(256), 0, stream>>>(F, A, flags, adj, rowsum, n, d);

    dsq_kernel<<<dim3((n + 255) / 256), dim3(256), 0, stream>>>(rowsum, dsq, n);

    dim3 gridN((n + 4095) / 4096, n);
    norm_kernel<<<gridN, dim3(256), 0, stream>>>(adj, dsq, out, n);
}